// Round 1
// 554.891 us; speedup vs baseline: 1.1527x; 1.1527x over previous
//
#include <hip/hip_runtime.h>
#include <math.h>

// Problem constants
#define HH 256
#define WW 256
#define HW 65536
#define EPS 1e-5f

typedef __attribute__((ext_vector_type(8))) short short8;
typedef __attribute__((ext_vector_type(16))) float f32x16;

__device__ __forceinline__ float bf2f(unsigned short u) {
    union { unsigned int i; float f; } c; c.i = ((unsigned int)u) << 16; return c.f;
}
__device__ __forceinline__ unsigned short f2bf(float f) {
    union { float f; unsigned int i; } c; c.f = f;
    return (unsigned short)((c.i + 0x7FFFu + ((c.i >> 16) & 1u)) >> 16);
}
// pack two f32 -> (bf16(a) | bf16(b)<<16), single VOP3 (RNE)
__device__ __forceinline__ unsigned int pkbf(float a, float b) {
    unsigned int r;
    asm("v_cvt_pk_bf16_f32 %0, %1, %2" : "=v"(r) : "v"(a), "v"(b));
    return r;
}

// ---------------------------------------------------------------------------
// Kernel 0: weights fp32 -> bf16 B-fragment layout, one tap per block.
//   wf[t][kg][co][j]: flat t*4096 + kg*512 + co*8 + j  (ci = kg*8+j)
// ---------------------------------------------------------------------------
__global__ void wprep_kernel(const float* __restrict__ w, unsigned short* __restrict__ wf)
{
    const int t = blockIdx.x;                 // tap 0..8
    for (int i = threadIdx.x; i < 4096; i += 256) {
        int kg = i >> 9;
        int r  = i & 511;
        int co = r >> 3;
        int j  = r & 7;
        int ci = kg * 8 + j;
        wf[t * 4096 + i] = f2bf(w[co * 576 + ci * 9 + t]);
    }
}

// ---------------------------------------------------------------------------
// Kernel 1: FUSED conv(3x3, MFMA implicit GEMM) + full epilogue.
//   Out tile 32x8 per block. x staged DIRECTLY from fp32 NCHW (transpose
//   kernel eliminated): 36x12 halo, per-task 8 plane-strided dword loads
//   (row-contiguous across the wave) packed to bf16 granules with
//   v_cvt_pk_bf16_f32, XOR-swizzled into LDS.
//   K-loop unchanged: B-frags in registers, zero barriers.
//   x_conv writeback: channel-pair packing via shfl_xor + cvt_pk -> b32
//   stores covering full 128B bank rows (kills the 8-way b16 conflicts).
//   Epilogue: pass1 computes per-group stats + channel max of x_conv;
//   M = max+1 bounds v = x_conv + tanh*gate (|fused|<1), so LSE needs a
//   single exp per channel with no serial rescale chain. tanh uses
//   v_rcp_f32 instead of IEEE divide. Swizzle addressing XOR-distributed:
//   addr = base ^ (kg<<4).
//   LDS: xs 55296 B -> 2 blocks/CU.
// ---------------------------------------------------------------------------
__global__ __launch_bounds__(256, 2)
void conv_fused_kernel(const float* __restrict__ x,
                       const unsigned short* __restrict__ wf,
                       const float* __restrict__ bias,
                       const float* __restrict__ w,
                       const float* __restrict__ gs,
                       const float* __restrict__ gb,
                       float* __restrict__ out)
{
    __shared__ unsigned short xs[432 * 64];        // x tile; reused for x_conv (340*64)
    char* xsb = (char*)xs;

    const int tid = threadIdx.x;
    const int tx  = blockIdx.x * 32;
    const int ty  = blockIdx.y * 8;
    const int b   = blockIdx.z;
    const size_t bHW = (size_t)b * HW;

    // ---- stage x tile 36x12 (origin tx-2, ty-2) from fp32 NCHW ----
    const float* xb = x + (size_t)b * 64 * HW;
#pragma unroll
    for (int it = 0; it < 16; ++it) {
        int g   = tid + it * 256;                  // kg = g>>9, pix = g&511
        int pix = g & 511;
        if (pix < 432) {
            int kg = g >> 9;
            int hy = (int)((unsigned)pix / 36u);
            int hx = pix - hy * 36;
            int gy = ty + hy - 2;
            int gx = tx + hx - 2;
            float v[8];
#pragma unroll
            for (int j = 0; j < 8; ++j) v[j] = 0.f;
            if (((unsigned)gy < (unsigned)HH) && ((unsigned)gx < (unsigned)WW)) {
                const float* p = xb + (size_t)kg * 8 * HW + gy * WW + gx;
#pragma unroll
                for (int j = 0; j < 8; ++j) v[j] = p[j * HW];
            }
            uint4 d;
            d.x = pkbf(v[0], v[1]);
            d.y = pkbf(v[2], v[3]);
            d.z = pkbf(v[4], v[5]);
            d.w = pkbf(v[6], v[7]);
            *(uint4*)(xsb + pix * 128 + (((pix & 7) ^ kg) << 4)) = d;
        }
    }
    __syncthreads();

    const int lane = tid & 63;
    const int wv   = tid >> 6;
    const int m    = lane & 31;
    const int half = lane >> 5;
    const int nt   = (wv < 3) ? 3 : 2;   // M-tiles this wave owns
    const int t0   = wv * 3;

    // per-lane base pixel index in the 36-wide staging grid, per M-tile
    int pb[3];
#pragma unroll
    for (int i = 0; i < 3; ++i) {
        int p = (t0 + i) * 32 + m;
        if (p > 339) p = 339;            // clamp (results discarded at store)
        int py = (int)((unsigned)p / 34u);
        pb[i] = py * 36 + (p - py * 34);
    }

    f32x16 acc[3][2];
#pragma unroll
    for (int i = 0; i < 3; ++i)
#pragma unroll
        for (int n = 0; n < 2; ++n)
#pragma unroll
            for (int r = 0; r < 16; ++r) acc[i][n][r] = 0.f;

    // ---- K-loop: kg-outer, B-frags in registers, no barriers ----
#pragma unroll 1
    for (int ks = 0; ks < 4; ++ks) {
        const int kg = ks * 2 + half;
        const unsigned short* wfk = wf + kg * 512 + m * 8;
        short8 bfr[9][2];
#pragma unroll
        for (int t9 = 0; t9 < 9; ++t9) {
            bfr[t9][0] = *(const short8*)(wfk + t9 * 4096);
            bfr[t9][1] = *(const short8*)(wfk + t9 * 4096 + 256);
        }
#pragma unroll
        for (int t9 = 0; t9 < 9; ++t9) {
            const int off = (t9 / 3) * 36 + (t9 - 3 * (t9 / 3));
#pragma unroll
            for (int i = 0; i < 3; ++i) {
                if (i < nt) {
                    int pi = pb[i] + off;
                    short8 a = *(const short8*)(xs + (pi * 8 + (kg ^ (pi & 7))) * 8);
                    acc[i][0] = __builtin_amdgcn_mfma_f32_32x32x16_bf16(a, bfr[t9][0], acc[i][0], 0, 0, 0);
                    acc[i][1] = __builtin_amdgcn_mfma_f32_32x32x16_bf16(a, bfr[t9][1], acc[i][1], 0, 0, 0);
                }
            }
        }
    }
    __syncthreads();   // all a-reads done before xs is overwritten

    // ---- write x_conv (+bias; zero outside image) into xs (34x10 grid) ----
    // channel-pair packing: even lane m packs acc0 chans (m,m+1); odd lane m
    // packs acc1 chans (31+m, 32+m). One b32 store per lane per reg ->
    // 64 lanes cover two full 128B bank rows (2-phase, conflict-free).
    const float bv0 = bias[m];
    const float bv1 = bias[32 + m];
    const bool odd  = m & 1;
    const int  kgw  = odd ? (4 + (m >> 3)) : (m >> 3);
#pragma unroll
    for (int i = 0; i < 3; ++i) {
        if (i < nt) {
            const int p0  = (t0 + i) * 32;              // wave-uniform
            const int pyA = (int)((unsigned)p0 / 34u);  // scalar div
            const int bnd = pyA * 34 + 34;
            const int pxA = p0 - pyA * 34;
#pragma unroll
            for (int reg = 0; reg < 16; ++reg) {
                int row = (reg & 3) + 8 * (reg >> 2) + 4 * half;
                int p   = p0 + row;
                bool hi = p >= bnd;
                int py  = pyA + (hi ? 1 : 0);
                int px  = pxA + row - (hi ? 34 : 0);
                int gy  = ty + py - 1;
                int gx  = tx + px - 1;
                bool inr = (p < 340) & ((unsigned)gy < (unsigned)HH) &
                           ((unsigned)gx < (unsigned)WW);
                float v0 = inr ? (acc[i][0][reg] + bv0) : 0.f;
                float v1 = inr ? (acc[i][1][reg] + bv1) : 0.f;
                float e0 = __shfl_xor(v0, 1, 64);       // partner's acc0 value
                float e1 = __shfl_xor(v1, 1, 64);       // partner's acc1 value
                float lo  = odd ? e1 : v0;
                float hiv = odd ? v1 : e0;
                unsigned int pk = pkbf(lo, hiv);
                if (p < 340) {
                    *(unsigned int*)(xsb + p * 128 + (((p & 7) << 4) ^ (kgw << 4))
                                         + ((m & 6) << 1)) = pk;
                }
            }
        }
    }
    __syncthreads();

    // ---- epilogue: one thread per output pixel (32x8) ----
    const int lx = tid & 31;
    const int ly = tid >> 5;

    // 9 neighborhood base byte-addresses; per-kg addr = base ^ (kg<<4)
    int base9[9];
#pragma unroll
    for (int dy = 0; dy < 3; ++dy)
#pragma unroll
        for (int dx = 0; dx < 3; ++dx) {
            int pl = (ly + dy) * 34 + (lx + dx);
            base9[dy * 3 + dx] = pl * 128 + ((pl & 7) << 4);
        }

    // pass 1: per-group stats + channel max of x_conv (center only)
    float meanA[8], invA[8];
    float vmax = -INFINITY;
#pragma unroll
    for (int kg = 0; kg < 8; ++kg) {
        short8 c8 = *(const short8*)(xsb + (base9[4] ^ (kg << 4)));
        float s = 0.f, s2 = 0.f;
#pragma unroll
        for (int c = 0; c < 8; ++c) {
            float xv = bf2f((unsigned short)c8[c]);
            s += xv;
            s2 = fmaf(xv, xv, s2);
            vmax = fmaxf(vmax, xv);
        }
        float mean = s * 0.125f;
        meanA[kg]  = mean;
        invA[kg]   = rsqrtf(fmaxf(s2 * 0.125f - mean * mean, 0.f) + EPS);
    }
    // |tanh*gate| < 1  =>  v = x_conv + fused < vmax + 1 = M (safe LSE bound)
    const float M = vmax + 1.0f;
    float ssum = 0.f;

    // pass 2: diag conv + activation + single-exp LSE
#pragma unroll
    for (int kg = 0; kg < 8; ++kg) {
        short8 n9[9];
#pragma unroll
        for (int k = 0; k < 9; ++k)
            n9[k] = *(const short8*)(xsb + (base9[k] ^ (kg << 4)));
        const float mean = meanA[kg];
        const float inv  = invA[kg];
#pragma unroll
        for (int c = 0; c < 8; ++c) {
            int ch = kg * 8 + c;
            float a = bias[ch];                       // uniform -> s_load
#pragma unroll
            for (int k = 0; k < 9; ++k)
                a = fmaf(w[ch * 585 + k], bf2f((unsigned short)n9[k][c]), a);
            float nrm  = (a - mean) * inv * gs[ch] + gb[ch];
            float gate = fminf(fmaxf((nrm + 3.f) * (1.f / 6.f), 0.f), 1.f);
            float e    = __expf(2.f * nrm);
            float th   = 1.f - 2.f * __builtin_amdgcn_rcpf(e + 1.f);
            float xv   = bf2f((unsigned short)n9[4][c]);
            ssum += __expf(xv + th * gate - M);
        }
    }

    out[bHW + (ty + ly) * WW + tx + lx] = M + __logf(ssum);
}

// ---------------------------------------------------------------------------
extern "C" void kernel_launch(void* const* d_in, const int* in_sizes, int n_in,
                              void* d_out, int out_size, void* d_ws, size_t ws_size,
                              hipStream_t stream)
{
    (void)in_sizes; (void)n_in; (void)out_size; (void)ws_size;
    const float* x   = (const float*)d_in[0];
    const float* w   = (const float*)d_in[1];
    const float* cbp = (const float*)d_in[2];
    const float* gsp = (const float*)d_in[3];
    const float* gbp = (const float*)d_in[4];
    float* out = (float*)d_out;

    unsigned short* wfp = (unsigned short*)d_ws;   // 73728 B B-fragment weights

    wprep_kernel<<<dim3(9), dim3(256), 0, stream>>>(w, wfp);
    conv_fused_kernel<<<dim3(8, 32, 16), dim3(256), 0, stream>>>(x, wfp, cbp, w, gsp, gbp, out);
}